// Round 6
// baseline (3820.989 us; speedup 1.0000x reference)
//
#include <hip/hip_runtime.h>
#include <cstdint>

#define NB 256
#define NT 128
#define NS 128
#define NH 256

#define NTHR 512
#define NWG  256
#define NGRP 64
#define GPW  4      // wgs per group
#define GBAT 4      // batch elems per group
#define UPW  64     // hidden units per wg

// ws layout in uint32 words
#define HC_OFF  0        // [2 parity][64 group][4 b][256 u] = 131072 words (f16x2 h,c)
#define FLG_OFF 131072   // [64 group][4 src][16] = 4096 words

typedef _Float16 f16;
typedef _Float16 f16x2 __attribute__((ext_vector_type(2)));
typedef _Float16 f16x8 __attribute__((ext_vector_type(8)));
typedef float    f32x4 __attribute__((ext_vector_type(4)));

#define SAH 528   // wahp/hcp row stride in f16 (16B-aligned, bank-spread)
#define SAG 392   // agxp row stride in f16

__device__ __forceinline__ f16x2 pk(float a, float b) {
  f16x2 r; r.x = (f16)a; r.y = (f16)b; return r;
}
__device__ __forceinline__ f16x8 pack8(const float* s) {
  float4 v0 = *(const float4*)s, v1 = *(const float4*)(s + 4);
  f16x8 r;
  r[0] = (f16)v0.x; r[1] = (f16)v0.y; r[2] = (f16)v0.z; r[3] = (f16)v0.w;
  r[4] = (f16)v1.x; r[5] = (f16)v1.y; r[6] = (f16)v1.z; r[7] = (f16)v1.w;
  return r;
}
__device__ __forceinline__ void awr(uint32_t* p, uint32_t v) {
  __hip_atomic_store(p, v, __ATOMIC_RELAXED, __HIP_MEMORY_SCOPE_AGENT);
}
__device__ __forceinline__ uint32_t ard(uint32_t* p) {
  return __hip_atomic_load(p, __ATOMIC_RELAXED, __HIP_MEMORY_SCOPE_AGENT);
}

struct __align__(16) Sm {
  f16   wahp[128 * SAH];   // 135168 B  W_ah f16 [t'][k], padded stride
  f16   hcp[5 * SAH];      // 5280 B    [b][h(0:256)|c(256:512)], row 4 = zeros
  f16   agxp[5 * SAG];     // 3920 B    [b][wx(0:128)|h(128:384)], row 4 = zeros
  float P[128 * 5];        // 2560 B    exp(2*hpart): [t'][b]
  float scp[4 * 128];      // 2048 B    scores [b][n]
  float gacc[256 * 4];     // 4096 B    gate sums [lr][b]
  float gbias[256];        // 1024
  float cbuf[256];         // 1024      [ul*4+b]
  float w2a[128];          // 512
  float bah[128];          // 512
};

__global__ void enc_init(uint32_t* ws) {
  int i = blockIdx.x * blockDim.x + threadIdx.x;
  if (i < 65536) ws[HC_OFF + i] = 0u;     // zero h,c parity 0
  if (i < 4096)  ws[FLG_OFF + i] = 0u;    // zero flags
}

__global__ __launch_bounds__(NTHR, 1) void enc_main(
    const float* __restrict__ x,    const float* __restrict__ W_ah,
    const float* __restrict__ b_ah, const float* __restrict__ W_ai,
    const float* __restrict__ b_ai, const float* __restrict__ W_a,
    const float* __restrict__ b_a,  const float* __restrict__ W_ih,
    const float* __restrict__ W_hh, const float* __restrict__ b_ih,
    const float* __restrict__ b_hh, float* __restrict__ out_iw,
    float* __restrict__ out_ie,     uint32_t* __restrict__ ws)
{
  __shared__ Sm sm;
  const int tid  = threadIdx.x;
  const int wg   = blockIdx.x;
  const int xcd  = wg & 7, slot = wg >> 3;
  const int g    = xcd * 8 + (slot >> 2);   // group 0..63 (co-XCD heuristic, perf-only)
  const int gid  = slot & 3;                // member 0..3
  const int b0   = g * GBAT;
  const int u0   = gid * UPW;

  const int wv = tid >> 6, ln = tid & 63;
  const int bn = ln & 15, kq = ln >> 4;

  // ---- persistent gate-weight B-fragments: wave wv owns local rows wv*32..+31 ----
  // local row lr -> global gate row: (lr>>6)*256 + u0 + (lr&63)
  f16x8 wfrag[2][12];
  #pragma unroll
  for (int tt = 0; tt < 2; ++tt) {
    const int lr = wv * 32 + tt * 16 + bn;
    const int grow = (lr >> 6) * 256 + u0 + (lr & 63);
    #pragma unroll
    for (int kk = 0; kk < 4; ++kk)
      wfrag[tt][kk] = pack8(W_ih + (size_t)grow * NS + kk * 32 + kq * 8);
    #pragma unroll
    for (int kk = 4; kk < 12; ++kk)
      wfrag[tt][kk] = pack8(W_hh + (size_t)grow * NH + (kk - 4) * 32 + kq * 8);
  }

  // ---- stage W_ah into LDS f16 (padded stride) ----
  #pragma unroll
  for (int i = 0; i < 16; ++i) {
    int idx = i * NTHR + tid;          // 8192 chunks of 8 f16
    int r = idx >> 6, c = idx & 63;
    f16x8 v = pack8(W_ah + (size_t)r * 512 + c * 8);
    *(f16x8*)&sm.wahp[(size_t)r * SAH + c * 8] = v;
  }
  if (tid < 256) {
    int grow = (tid >> 6) * 256 + u0 + (tid & 63);
    sm.gbias[tid] = b_ih[grow] + b_hh[grow];
    sm.cbuf[tid] = 0.f;
  }
  if (tid < 128) { sm.w2a[tid] = 2.f * W_a[tid]; sm.bah[tid] = b_ah[tid]; }
  if (tid < 512) sm.hcp[4 * SAH + tid] = (f16)0.f;   // zero row 4 (batch pad)
  if (tid < 384) sm.agxp[4 * SAG + tid] = (f16)0.f;

  // ---- per-thread E (exp(2*ipart)) for (n = tid&127, bq = tid>>7) ----
  const int n_s = tid & 127, bq_s = tid >> 7;
  float ev;
  {
    const float* xb = x + (size_t)(b0 + bq_s) * NT * NS;
    float a = 0.f;
    #pragma unroll 4
    for (int t = 0; t < NT; ++t) a = fmaf(xb[(size_t)t * NS + n_s], W_ai[t], a);
    ev = __expf(2.f * (a + b_ai[0]));
  }
  float S0;
  { float s = b_a[0]; for (int i = 0; i < 128; ++i) s += W_a[i]; S0 = s; }

  uint32_t* flg_my = ws + FLG_OFF + (g * 4 + gid) * 16;
  __syncthreads();

  for (int t = 0; t < NT; ++t) {
    const int par = t & 1;
    // ---- prefetch x_t for softmax (waves 0-3, batch = wv) ----
    float xv0 = 0.f, xv1 = 0.f;
    if (wv < 4) {
      const float* xr = x + ((size_t)(b0 + wv) * NT + t) * NS;
      xv0 = xr[ln]; xv1 = xr[ln + 64];
    }
    // ---- wait partner flags (per-wave) + read h,c ----
    {
      const int src = wv >> 1, half = wv & 1;
      uint32_t* fl = ws + FLG_OFF + (g * 4 + src) * 16;
      if (t > 0) {
        while (__hip_atomic_load(fl, __ATOMIC_ACQUIRE, __HIP_MEMORY_SCOPE_AGENT) <
               (uint32_t)t)
          __builtin_amdgcn_s_sleep(1);
      }
      uint32_t* hcb = ws + HC_OFF + ((size_t)par * NGRP + g) * 1024;
      const int u = src * 64 + ln;
      #pragma unroll
      for (int jj = 0; jj < 2; ++jj) {
        const int b = half * 2 + jj;
        uint32_t v = ard(hcb + b * 256 + u);
        f16x2 pv = __builtin_bit_cast(f16x2, v);
        sm.hcp[b * SAH + u] = pv.x;
        sm.hcp[b * SAH + 256 + u] = pv.y;
        sm.agxp[b * SAG + 128 + u] = pv.x;
      }
    }
    __syncthreads();
    // ---- hpart MFMA: wave wv owns t' rows wv*16..+15; A=W_ah, B=hc ----
    {
      f32x4 acc = {0.f, 0.f, 0.f, 0.f};
      const int br = (bn < 4) ? bn : 4;
      #pragma unroll
      for (int kk = 0; kk < 16; ++kk) {
        f16x8 a = *(const f16x8*)&sm.wahp[(size_t)(wv * 16 + bn) * SAH + kk * 32 + kq * 8];
        f16x8 b = *(const f16x8*)&sm.hcp[(size_t)br * SAH + kk * 32 + kq * 8];
        acc = __builtin_amdgcn_mfma_f32_16x16x32_f16(a, b, acc, 0, 0, 0);
      }
      if (bn < 4) {
        const int tp0 = wv * 16 + (ln >> 4) * 4;
        #pragma unroll
        for (int r = 0; r < 4; ++r)
          sm.P[(tp0 + r) * 5 + bn] = __expf(2.f * (acc[r] + sm.bah[tp0 + r]));
      }
    }
    __syncthreads();
    // ---- score: thread (n_s, bq_s): S0 - sum_t' w2a/(1+P*E) ----
    {
      float s = 0.f;
      #pragma unroll 8
      for (int tp = 0; tp < 128; ++tp) {
        float pe = fmaf(sm.P[tp * 5 + bq_s], ev, 1.f);
        s = fmaf(sm.w2a[tp], __builtin_amdgcn_rcpf(pe), s);
      }
      sm.scp[bq_s * 128 + n_s] = S0 - s;
    }
    __syncthreads();
    // ---- softmax + wx: wave wv < 4 handles batch wv ----
    if (wv < 4) {
      float sA = sm.scp[wv * 128 + ln], sB = sm.scp[wv * 128 + ln + 64];
      float m = fmaxf(sA, sB);
      #pragma unroll
      for (int o = 32; o; o >>= 1) m = fmaxf(m, __shfl_xor(m, o));
      float eA = __expf(sA - m), eB = __expf(sB - m);
      float ss = eA + eB;
      #pragma unroll
      for (int o = 32; o; o >>= 1) ss += __shfl_xor(ss, o);
      float rs = 1.f / ss;
      float wxA = eA * rs * xv0, wxB = eB * rs * xv1;
      sm.agxp[wv * SAG + ln] = (f16)wxA;
      sm.agxp[wv * SAG + ln + 64] = (f16)wxB;
      if (wv == gid) {
        float* ow = out_iw + ((size_t)(b0 + wv) * NT + t) * NS;
        ow[ln] = wxA; ow[ln + 64] = wxB;
      }
    }
    __syncthreads();
    // ---- gates MFMA: A=act (m=batch), B=wfrag (n=rows) ----
    {
      const int br = (bn < 4) ? bn : 4;
      #pragma unroll
      for (int tt = 0; tt < 2; ++tt) {
        f32x4 acc = {0.f, 0.f, 0.f, 0.f};
        #pragma unroll
        for (int kk = 0; kk < 12; ++kk) {
          f16x8 a = *(const f16x8*)&sm.agxp[(size_t)br * SAG + kk * 32 + kq * 8];
          acc = __builtin_amdgcn_mfma_f32_16x16x32_f16(a, wfrag[tt][kk], acc, 0, 0, 0);
        }
        if (ln < 16)
          *(f32x4*)&sm.gacc[(wv * 32 + tt * 16 + ln) * 4] = acc;
      }
    }
    __syncthreads();
    // ---- LSTM pointwise + publish h,c (own 64 units x 4 batches) ----
    if (tid < 256) {
      const int b = tid >> 6, ul = tid & 63;
      float gi = sm.gacc[(ul) * 4 + b]       + sm.gbias[ul];
      float gf = sm.gacc[(64 + ul) * 4 + b]  + sm.gbias[64 + ul];
      float gg = sm.gacc[(128 + ul) * 4 + b] + sm.gbias[128 + ul];
      float go = sm.gacc[(192 + ul) * 4 + b] + sm.gbias[192 + ul];
      float ii = 1.f / (1.f + __expf(-gi));
      float ff = 1.f / (1.f + __expf(-gf));
      float gt = 1.f - 2.f / (1.f + __expf(2.f * gg));
      float oo = 1.f / (1.f + __expf(-go));
      float c2 = ff * sm.cbuf[ul * 4 + b] + ii * gt;
      float h2 = oo * (1.f - 2.f / (1.f + __expf(2.f * c2)));
      sm.cbuf[ul * 4 + b] = c2;
      out_ie[((size_t)(b0 + b) * NT + t) * NH + u0 + ul] = h2;
      uint32_t* dst = ws + HC_OFF + ((size_t)(1 - par) * NGRP + g) * 1024 +
                      b * 256 + u0 + ul;
      awr(dst, __builtin_bit_cast(uint32_t, pk(h2, c2)));
    }
    __syncthreads();   // drains each wave's stores (vmcnt 0) before flag
    if (tid == 0)
      __hip_atomic_store(flg_my, (uint32_t)(t + 1), __ATOMIC_RELEASE,
                         __HIP_MEMORY_SCOPE_AGENT);
  }
}

extern "C" void kernel_launch(void* const* d_in, const int* in_sizes, int n_in,
                              void* d_out, int out_size, void* d_ws, size_t ws_size,
                              hipStream_t stream) {
  const float* x    = (const float*)d_in[0];
  const float* W_ah = (const float*)d_in[1];
  const float* b_ah = (const float*)d_in[2];
  const float* W_ai = (const float*)d_in[3];
  const float* b_ai = (const float*)d_in[4];
  const float* W_a  = (const float*)d_in[5];
  const float* b_a  = (const float*)d_in[6];
  const float* W_ih = (const float*)d_in[7];
  const float* W_hh = (const float*)d_in[8];
  const float* b_ih = (const float*)d_in[9];
  const float* b_hh = (const float*)d_in[10];
  float* out_iw = (float*)d_out;
  float* out_ie = (float*)d_out + (size_t)NB * NT * NS;
  uint32_t* ws = (uint32_t*)d_ws;

  hipLaunchKernelGGL(enc_init, dim3(256), dim3(256), 0, stream, ws);
  hipLaunchKernelGGL(enc_main, dim3(NWG), dim3(NTHR), 0, stream,
                     x, W_ah, b_ah, W_ai, b_ai, W_a, b_a, W_ih, W_hh, b_ih, b_hh,
                     out_iw, out_ie, ws);
}

// Round 7
// 807.642 us; speedup vs baseline: 4.7310x; 4.7310x over previous
//
#include <hip/hip_runtime.h>
#include <cstdint>

#define NB 256
#define NT 128
#define NS 128
#define NH 256

#define NTHR 512
#define NWG  256
#define NGRP 64
#define GPW  4      // wgs per group
#define GBAT 4      // batch elems per group
#define UPW  64     // hidden units per wg

// ws layout in uint32 words
#define HC_OFF  0        // [2 parity][64 group][4 b][256 u] = 131072 words (f16x2 h,c)
#define CNT_OFF 131072   // [64 group][16] counters

typedef _Float16 f16;
typedef _Float16 f16x2 __attribute__((ext_vector_type(2)));
typedef _Float16 f16x8 __attribute__((ext_vector_type(8)));
typedef float    f32x4 __attribute__((ext_vector_type(4)));

#define SAH 528   // wahp/hcp row stride in f16 (16B-aligned, bank-spread)
#define SAG 392   // agxp row stride in f16

__device__ __forceinline__ f16x2 pk(float a, float b) {
  f16x2 r; r.x = (f16)a; r.y = (f16)b; return r;
}
__device__ __forceinline__ f16x8 pack8(const float* s) {
  float4 v0 = *(const float4*)s, v1 = *(const float4*)(s + 4);
  f16x8 r;
  r[0] = (f16)v0.x; r[1] = (f16)v0.y; r[2] = (f16)v0.z; r[3] = (f16)v0.w;
  r[4] = (f16)v1.x; r[5] = (f16)v1.y; r[6] = (f16)v1.z; r[7] = (f16)v1.w;
  return r;
}
__device__ __forceinline__ void awr(uint32_t* p, uint32_t v) {
  __hip_atomic_store(p, v, __ATOMIC_RELAXED, __HIP_MEMORY_SCOPE_AGENT);
}
__device__ __forceinline__ uint32_t ard(uint32_t* p) {
  return __hip_atomic_load(p, __ATOMIC_RELAXED, __HIP_MEMORY_SCOPE_AGENT);
}
__device__ __forceinline__ void cinc(uint32_t* p) {
  __hip_atomic_fetch_add(p, 1u, __ATOMIC_RELAXED, __HIP_MEMORY_SCOPE_AGENT);
}
__device__ __forceinline__ void cwait(uint32_t* p, uint32_t tgt) {
  while (ard(p) < tgt) __builtin_amdgcn_s_sleep(1);
}

struct __align__(16) Sm {
  f16   wahp[128 * SAH];   // 135168 B  W_ah f16 [t'][k], padded stride
  f16   hcp[5 * SAH];      // 5280 B    [b][h(0:256)|c(256:512)], row 4 = zeros
  f16   agxp[5 * SAG];     // 3920 B    [b][wx(0:128)|h(128:384)], row 4 = zeros
  float P[128 * 5];        // 2560 B    exp(2*hpart): [t'][b]
  float scp[4 * 128];      // 2048 B    scores [b][n]
  float gacc[256 * 4];     // 4096 B    gate sums [lr][b]
  float gbias[256];        // 1024
  float cbuf[256];         // 1024      [ul*4+b]
  float w2a[128];          // 512
  float bah[128];          // 512
};

__global__ void enc_init(uint32_t* ws) {
  int i = blockIdx.x * blockDim.x + threadIdx.x;
  if (i < 65536) ws[HC_OFF + i] = 0u;     // zero h,c parity 0
  if (i < 1024)  ws[CNT_OFF + i] = 0u;    // zero counters
}

__global__ __launch_bounds__(NTHR, 1) void enc_main(
    const float* __restrict__ x,    const float* __restrict__ W_ah,
    const float* __restrict__ b_ah, const float* __restrict__ W_ai,
    const float* __restrict__ b_ai, const float* __restrict__ W_a,
    const float* __restrict__ b_a,  const float* __restrict__ W_ih,
    const float* __restrict__ W_hh, const float* __restrict__ b_ih,
    const float* __restrict__ b_hh, float* __restrict__ out_iw,
    float* __restrict__ out_ie,     uint32_t* __restrict__ ws)
{
  __shared__ Sm sm;
  const int tid  = threadIdx.x;
  const int wg   = blockIdx.x;
  const int xcd  = wg & 7, slot = wg >> 3;
  const int g    = xcd * 8 + (slot >> 2);   // group 0..63 (co-XCD heuristic, perf-only)
  const int gid  = slot & 3;                // member 0..3
  const int b0   = g * GBAT;
  const int u0   = gid * UPW;

  const int wv = tid >> 6, ln = tid & 63;
  const int bn = ln & 15, kq = ln >> 4;

  uint32_t* cnt = ws + CNT_OFF + g * 16;

  // ---- persistent gate-weight B-fragments: wave wv owns local rows wv*32..+31 ----
  // local row lr -> global gate row: (lr>>6)*256 + u0 + (lr&63)
  f16x8 wfrag[2][12];
  #pragma unroll
  for (int tt = 0; tt < 2; ++tt) {
    const int lr = wv * 32 + tt * 16 + bn;
    const int grow = (lr >> 6) * 256 + u0 + (lr & 63);
    #pragma unroll
    for (int kk = 0; kk < 4; ++kk)
      wfrag[tt][kk] = pack8(W_ih + (size_t)grow * NS + kk * 32 + kq * 8);
    #pragma unroll
    for (int kk = 4; kk < 12; ++kk)
      wfrag[tt][kk] = pack8(W_hh + (size_t)grow * NH + (kk - 4) * 32 + kq * 8);
  }

  // ---- stage W_ah into LDS f16 (padded stride) ----
  #pragma unroll
  for (int i = 0; i < 16; ++i) {
    int idx = i * NTHR + tid;          // 8192 chunks of 8 f16
    int r = idx >> 6, c = idx & 63;
    f16x8 v = pack8(W_ah + (size_t)r * 512 + c * 8);
    *(f16x8*)&sm.wahp[(size_t)r * SAH + c * 8] = v;
  }
  if (tid < 256) {
    int grow = (tid >> 6) * 256 + u0 + (tid & 63);
    sm.gbias[tid] = b_ih[grow] + b_hh[grow];
    sm.cbuf[tid] = 0.f;
  }
  if (tid < 128) { sm.w2a[tid] = 2.f * W_a[tid]; sm.bah[tid] = b_ah[tid]; }
  if (tid < 512) sm.hcp[4 * SAH + tid] = (f16)0.f;   // zero row 4 (batch pad)
  if (tid < 384) sm.agxp[4 * SAG + tid] = (f16)0.f;

  // ---- per-thread E (exp(2*ipart)) for (n = tid&127, bq = tid>>7) ----
  const int n_s = tid & 127, bq_s = tid >> 7;
  float ev;
  {
    const float* xb = x + (size_t)(b0 + bq_s) * NT * NS;
    float a = 0.f;
    #pragma unroll 4
    for (int t = 0; t < NT; ++t) a = fmaf(xb[(size_t)t * NS + n_s], W_ai[t], a);
    ev = __expf(2.f * (a + b_ai[0]));
  }
  float S0;
  { float s = b_a[0]; for (int i = 0; i < 128; ++i) s += W_a[i]; S0 = s; }

  __syncthreads();

  for (int t = 0; t < NT; ++t) {
    const int par = t & 1;
    // ---- prefetch x_t for softmax (waves 0-3, batch = wv) ----
    float xv0 = 0.f, xv1 = 0.f;
    if (wv < 4) {
      const float* xr = x + ((size_t)(b0 + wv) * NT + t) * NS;
      xv0 = xr[ln]; xv1 = xr[ln + 64];
    }
    // ---- single group sync: tid0 relaxed poll, barrier fan-out ----
    if (t > 0) {
      if (tid == 0) cwait(cnt, 4u * (uint32_t)t);
      __syncthreads();
    }
    // ---- read exchanged h,c (relaxed, spread across all waves) ----
    {
      uint32_t* hcb = ws + HC_OFF + ((size_t)par * NGRP + g) * 1024;
      #pragma unroll
      for (int i = 0; i < 2; ++i) {
        int w = i * NTHR + tid;          // [b(4)][u(256)]
        uint32_t v = ard(hcb + w);
        f16x2 pv = __builtin_bit_cast(f16x2, v);
        int b = w >> 8, u = w & 255;
        sm.hcp[b * SAH + u] = pv.x;
        sm.hcp[b * SAH + 256 + u] = pv.y;
        sm.agxp[b * SAG + 128 + u] = pv.x;
      }
    }
    __syncthreads();
    // ---- hpart MFMA: wave wv owns t' rows wv*16..+15; A=W_ah, B=hc ----
    {
      f32x4 acc = {0.f, 0.f, 0.f, 0.f};
      const int br = (bn < 4) ? bn : 4;
      #pragma unroll
      for (int kk = 0; kk < 16; ++kk) {
        f16x8 a = *(const f16x8*)&sm.wahp[(size_t)(wv * 16 + bn) * SAH + kk * 32 + kq * 8];
        f16x8 b = *(const f16x8*)&sm.hcp[(size_t)br * SAH + kk * 32 + kq * 8];
        acc = __builtin_amdgcn_mfma_f32_16x16x32_f16(a, b, acc, 0, 0, 0);
      }
      if (bn < 4) {
        const int tp0 = wv * 16 + (ln >> 4) * 4;
        #pragma unroll
        for (int r = 0; r < 4; ++r)
          sm.P[(tp0 + r) * 5 + bn] = __expf(2.f * (acc[r] + sm.bah[tp0 + r]));
      }
    }
    __syncthreads();
    // ---- score: thread (n_s, bq_s): S0 - sum_t' w2a/(1+P*E) ----
    {
      float s = 0.f;
      #pragma unroll 8
      for (int tp = 0; tp < 128; ++tp) {
        float pe = fmaf(sm.P[tp * 5 + bq_s], ev, 1.f);
        s = fmaf(sm.w2a[tp], __builtin_amdgcn_rcpf(pe), s);
      }
      sm.scp[bq_s * 128 + n_s] = S0 - s;
    }
    __syncthreads();
    // ---- softmax + wx: wave wv < 4 handles batch wv ----
    if (wv < 4) {
      float sA = sm.scp[wv * 128 + ln], sB = sm.scp[wv * 128 + ln + 64];
      float m = fmaxf(sA, sB);
      #pragma unroll
      for (int o = 32; o; o >>= 1) m = fmaxf(m, __shfl_xor(m, o));
      float eA = __expf(sA - m), eB = __expf(sB - m);
      float ss = eA + eB;
      #pragma unroll
      for (int o = 32; o; o >>= 1) ss += __shfl_xor(ss, o);
      float rs = 1.f / ss;
      float wxA = eA * rs * xv0, wxB = eB * rs * xv1;
      sm.agxp[wv * SAG + ln] = (f16)wxA;
      sm.agxp[wv * SAG + ln + 64] = (f16)wxB;
      if (wv == gid) {
        float* ow = out_iw + ((size_t)(b0 + wv) * NT + t) * NS;
        ow[ln] = wxA; ow[ln + 64] = wxB;
      }
    }
    __syncthreads();
    // ---- gates MFMA: A=act (m=batch), B=wfrag (n=rows) ----
    {
      const int br = (bn < 4) ? bn : 4;
      #pragma unroll
      for (int tt = 0; tt < 2; ++tt) {
        f32x4 acc = {0.f, 0.f, 0.f, 0.f};
        #pragma unroll
        for (int kk = 0; kk < 12; ++kk) {
          f16x8 a = *(const f16x8*)&sm.agxp[(size_t)br * SAG + kk * 32 + kq * 8];
          acc = __builtin_amdgcn_mfma_f32_16x16x32_f16(a, wfrag[tt][kk], acc, 0, 0, 0);
        }
        if (ln < 16)
          *(f32x4*)&sm.gacc[(wv * 32 + tt * 16 + ln) * 4] = acc;
      }
    }
    __syncthreads();
    // ---- LSTM pointwise + publish h,c (own 64 units x 4 batches) ----
    if (tid < 256) {
      const int b = tid >> 6, ul = tid & 63;
      float gi = sm.gacc[(ul) * 4 + b]       + sm.gbias[ul];
      float gf = sm.gacc[(64 + ul) * 4 + b]  + sm.gbias[64 + ul];
      float gg = sm.gacc[(128 + ul) * 4 + b] + sm.gbias[128 + ul];
      float go = sm.gacc[(192 + ul) * 4 + b] + sm.gbias[192 + ul];
      float ii = 1.f / (1.f + __expf(-gi));
      float ff = 1.f / (1.f + __expf(-gf));
      float gt = 1.f - 2.f / (1.f + __expf(2.f * gg));
      float oo = 1.f / (1.f + __expf(-go));
      float c2 = ff * sm.cbuf[ul * 4 + b] + ii * gt;
      float h2 = oo * (1.f - 2.f / (1.f + __expf(2.f * c2)));
      sm.cbuf[ul * 4 + b] = c2;
      out_ie[((size_t)(b0 + b) * NT + t) * NH + u0 + ul] = h2;
      uint32_t* dst = ws + HC_OFF + ((size_t)(1 - par) * NGRP + g) * 1024 +
                      b * 256 + u0 + ul;
      awr(dst, __builtin_bit_cast(uint32_t, pk(h2, c2)));
    }
    __syncthreads();   // drains all waves' publishes before the counter bump
    if (tid == 0) cinc(cnt);
  }
}

extern "C" void kernel_launch(void* const* d_in, const int* in_sizes, int n_in,
                              void* d_out, int out_size, void* d_ws, size_t ws_size,
                              hipStream_t stream) {
  const float* x    = (const float*)d_in[0];
  const float* W_ah = (const float*)d_in[1];
  const float* b_ah = (const float*)d_in[2];
  const float* W_ai = (const float*)d_in[3];
  const float* b_ai = (const float*)d_in[4];
  const float* W_a  = (const float*)d_in[5];
  const float* b_a  = (const float*)d_in[6];
  const float* W_ih = (const float*)d_in[7];
  const float* W_hh = (const float*)d_in[8];
  const float* b_ih = (const float*)d_in[9];
  const float* b_hh = (const float*)d_in[10];
  float* out_iw = (float*)d_out;
  float* out_ie = (float*)d_out + (size_t)NB * NT * NS;
  uint32_t* ws = (uint32_t*)d_ws;

  hipLaunchKernelGGL(enc_init, dim3(256), dim3(256), 0, stream, ws);
  hipLaunchKernelGGL(enc_main, dim3(NWG), dim3(NTHR), 0, stream,
                     x, W_ah, b_ah, W_ai, b_ai, W_a, b_a, W_ih, W_hh, b_ih, b_hh,
                     out_iw, out_ie, ws);
}

// Round 8
// 732.817 us; speedup vs baseline: 5.2141x; 1.1021x over previous
//
#include <hip/hip_runtime.h>
#include <cstdint>

#define NB 256
#define NT 128
#define NS 128
#define NH 256

#define NTHR 1024
#define NWG  256
#define NGRP 64
#define GBAT 4      // batch elems per group
#define UPW  64     // hidden units per wg

// ws layout in uint32 words
#define HC_OFF  0        // [2 parity][64 group][4 b][256 u] = 131072 words (f16x2 h,c)
#define CNT_OFF 131072   // [64 group][16] counters

typedef _Float16 f16;
typedef _Float16 f16x2 __attribute__((ext_vector_type(2)));
typedef _Float16 f16x8 __attribute__((ext_vector_type(8)));
typedef float    f32x4 __attribute__((ext_vector_type(4)));

#define SAH 528   // wahp/hcp row stride in f16 (16B-aligned, bank-spread)
#define SAG 392   // agxp row stride in f16

__device__ __forceinline__ f16x2 pk(float a, float b) {
  f16x2 r; r.x = (f16)a; r.y = (f16)b; return r;
}
__device__ __forceinline__ f16x8 pack8(const float* s) {
  float4 v0 = *(const float4*)s, v1 = *(const float4*)(s + 4);
  f16x8 r;
  r[0] = (f16)v0.x; r[1] = (f16)v0.y; r[2] = (f16)v0.z; r[3] = (f16)v0.w;
  r[4] = (f16)v1.x; r[5] = (f16)v1.y; r[6] = (f16)v1.z; r[7] = (f16)v1.w;
  return r;
}
__device__ __forceinline__ void awr(uint32_t* p, uint32_t v) {
  __hip_atomic_store(p, v, __ATOMIC_RELAXED, __HIP_MEMORY_SCOPE_AGENT);
}
__device__ __forceinline__ uint32_t ard(uint32_t* p) {
  return __hip_atomic_load(p, __ATOMIC_RELAXED, __HIP_MEMORY_SCOPE_AGENT);
}
__device__ __forceinline__ void cinc(uint32_t* p) {
  __hip_atomic_fetch_add(p, 1u, __ATOMIC_RELAXED, __HIP_MEMORY_SCOPE_AGENT);
}
__device__ __forceinline__ void cwait(uint32_t* p, uint32_t tgt) {
  while (ard(p) < tgt) __builtin_amdgcn_s_sleep(1);
}

struct __align__(16) Sm {
  f16   wahp[128 * SAH];   // 135168 B  W_ah f16 [t'][k], padded stride
  f16   hcp[5 * SAH];      // 5280 B    [b][h(0:256)|c(256:512)], row 4 = zeros
  f16   agxp[5 * SAG];     // 3920 B    [b][wx(0:128)|h(128:384)], row 4 = zeros
  float PW[128 * 5 * 2];   // 5120 B    [t'][b] pairs {exp(2*hpart), w2a}
  union {
    float pacc[8][2][16][4];  // hpart K-partials [tile][half][t'l][b]
    float sp[2][4][128];      // score t'-partials [ts][b][n]
  } u;                     // 4096 B
  float gacc[256 * 4];     // 4096 B    gate sums [lr][b]
  float gbias[256];        // 1024
  float cbuf[256];         // 1024      [ul*4+b]
  float w2a[128];          // 512
  float bah[128];          // 512
};

__global__ void enc_init(uint32_t* ws) {
  int i = blockIdx.x * blockDim.x + threadIdx.x;
  if (i < 65536) ws[HC_OFF + i] = 0u;     // zero h,c parity 0
  if (i < 1024)  ws[CNT_OFF + i] = 0u;    // zero counters
}

__global__ __launch_bounds__(NTHR, 4) void enc_main(
    const float* __restrict__ x,    const float* __restrict__ W_ah,
    const float* __restrict__ b_ah, const float* __restrict__ W_ai,
    const float* __restrict__ b_ai, const float* __restrict__ W_a,
    const float* __restrict__ b_a,  const float* __restrict__ W_ih,
    const float* __restrict__ W_hh, const float* __restrict__ b_ih,
    const float* __restrict__ b_hh, float* __restrict__ out_iw,
    float* __restrict__ out_ie,     uint32_t* __restrict__ ws)
{
  __shared__ Sm sm;
  const int tid  = threadIdx.x;
  const int wg   = blockIdx.x;
  const int xcd  = wg & 7, slot = wg >> 3;
  const int g    = xcd * 8 + (slot >> 2);   // group 0..63 (co-XCD heuristic, perf-only)
  const int gid  = slot & 3;                // member 0..3
  const int b0   = g * GBAT;
  const int u0   = gid * UPW;

  const int wv = tid >> 6, ln = tid & 63;
  const int bn = ln & 15, kq = ln >> 4;

  uint32_t* cnt = ws + CNT_OFF + g * 16;

  // ---- persistent gate-weight B-fragments: wave wv owns local rows wv*16..+15 ----
  // local row lr -> gate (lr>>6), unit u0 + (lr&63)
  f16x8 wfrag[12];
  {
    const int lr = wv * 16 + bn;
    const int grow = (lr >> 6) * 256 + u0 + (lr & 63);
    #pragma unroll
    for (int kk = 0; kk < 4; ++kk)
      wfrag[kk] = pack8(W_ih + (size_t)grow * NS + kk * 32 + kq * 8);
    #pragma unroll
    for (int kk = 4; kk < 12; ++kk)
      wfrag[kk] = pack8(W_hh + (size_t)grow * NH + (kk - 4) * 32 + kq * 8);
  }

  // ---- stage W_ah into LDS f16 (padded stride) ----
  #pragma unroll
  for (int i = 0; i < 8; ++i) {
    int idx = i * NTHR + tid;          // 8192 chunks of 8 f16
    int r = idx >> 6, c = idx & 63;
    f16x8 v = pack8(W_ah + (size_t)r * 512 + c * 8);
    *(f16x8*)&sm.wahp[(size_t)r * SAH + c * 8] = v;
  }
  if (tid < 256) {
    int grow = (tid >> 6) * 256 + u0 + (tid & 63);
    sm.gbias[tid] = b_ih[grow] + b_hh[grow];
    sm.cbuf[tid] = 0.f;
  }
  if (tid < 128) { sm.w2a[tid] = 2.f * W_a[tid]; sm.bah[tid] = b_ah[tid]; }
  if (tid < 512) sm.hcp[4 * SAH + tid] = (f16)0.f;   // zero row 4 (batch pad)
  if (tid < 384) sm.agxp[4 * SAG + tid] = (f16)0.f;

  // ---- per-thread E (exp(2*ipart)) for (n = tid&127, bq = (tid>>7)&3) ----
  const int n_s = tid & 127, bq_s = (tid >> 7) & 3, ts_s = tid >> 9;
  float ev;
  {
    const float* xb = x + (size_t)(b0 + bq_s) * NT * NS;
    float a = 0.f;
    #pragma unroll 4
    for (int t = 0; t < NT; ++t) a = fmaf(xb[(size_t)t * NS + n_s], W_ai[t], a);
    ev = __expf(2.f * (a + b_ai[0]));
  }
  float S0;
  { float s = b_a[0]; for (int i = 0; i < 128; ++i) s += W_a[i]; S0 = s; }

  __syncthreads();

  for (int t = 0; t < NT; ++t) {
    const int par = t & 1;
    // ---- prefetch x_t for softmax (waves 0-3, batch = wv) ----
    float xv0 = 0.f, xv1 = 0.f;
    if (wv < 4) {
      const float* xr = x + ((size_t)(b0 + wv) * NT + t) * NS;
      xv0 = xr[ln]; xv1 = xr[ln + 64];
    }
    // ---- single group sync: tid0 relaxed poll, barrier fan-out ----
    if (t > 0) {
      if (tid == 0) cwait(cnt, 4u * (uint32_t)t);
      __syncthreads();
    }
    // ---- read exchanged h,c (relaxed, 1 word/thread) ----
    {
      uint32_t* hcb = ws + HC_OFF + ((size_t)par * NGRP + g) * 1024;
      uint32_t v = ard(hcb + tid);
      f16x2 pv = __builtin_bit_cast(f16x2, v);
      int b = tid >> 8, u = tid & 255;
      sm.hcp[b * SAH + u] = pv.x;
      sm.hcp[b * SAH + 256 + u] = pv.y;
      sm.agxp[b * SAG + 128 + u] = pv.x;
    }
    __syncthreads();
    // ---- hpart MFMA split-K: wave = (tile = wv&7, half = wv>>3) ----
    {
      const int tile = wv & 7, half = wv >> 3;
      f32x4 acc = {0.f, 0.f, 0.f, 0.f};
      const int br = (bn < 4) ? bn : 4;
      #pragma unroll
      for (int j = 0; j < 8; ++j) {
        int kk = half * 8 + j;
        f16x8 a = *(const f16x8*)&sm.wahp[(size_t)(tile * 16 + bn) * SAH + kk * 32 + kq * 8];
        f16x8 b = *(const f16x8*)&sm.hcp[(size_t)br * SAH + kk * 32 + kq * 8];
        acc = __builtin_amdgcn_mfma_f32_16x16x32_f16(a, b, acc, 0, 0, 0);
      }
      if (bn < 4) {
        #pragma unroll
        for (int r = 0; r < 4; ++r)
          sm.u.pacc[tile][half][kq * 4 + r][bn] = acc[r];
      }
    }
    __syncthreads();
    // ---- P = exp(2*(sum partials + bah)), fused with w2a into PW pairs ----
    if (tid < 512) {
      int tl = tid >> 2, b = tid & 3;
      float p = sm.u.pacc[tl >> 4][0][tl & 15][b] + sm.u.pacc[tl >> 4][1][tl & 15][b];
      float pe = __expf(2.f * (p + sm.bah[tl]));
      sm.PW[(tl * 5 + b) * 2]     = pe;
      sm.PW[(tl * 5 + b) * 2 + 1] = sm.w2a[tl];
    }
    __syncthreads();
    // ---- score partials: thread (ts, bq, n) sums 64 t' terms ----
    {
      float s = 0.f;
      #pragma unroll 8
      for (int i = 0; i < 64; ++i) {
        int tp = ts_s * 64 + i;
        float2 pw = *(const float2*)&sm.PW[(tp * 5 + bq_s) * 2];
        float pe = fmaf(pw.x, ev, 1.f);
        s = fmaf(pw.y, __builtin_amdgcn_rcpf(pe), s);
      }
      sm.u.sp[ts_s][bq_s][n_s] = s;
    }
    __syncthreads();
    // ---- softmax + wx: wave wv < 4 handles batch wv ----
    if (wv < 4) {
      float sA = S0 - (sm.u.sp[0][wv][ln] + sm.u.sp[1][wv][ln]);
      float sB = S0 - (sm.u.sp[0][wv][ln + 64] + sm.u.sp[1][wv][ln + 64]);
      float m = fmaxf(sA, sB);
      #pragma unroll
      for (int o = 32; o; o >>= 1) m = fmaxf(m, __shfl_xor(m, o));
      float eA = __expf(sA - m), eB = __expf(sB - m);
      float ss = eA + eB;
      #pragma unroll
      for (int o = 32; o; o >>= 1) ss += __shfl_xor(ss, o);
      float rs = 1.f / ss;
      float wxA = eA * rs * xv0, wxB = eB * rs * xv1;
      sm.agxp[wv * SAG + ln] = (f16)wxA;
      sm.agxp[wv * SAG + ln + 64] = (f16)wxB;
      if (wv == gid) {
        float* ow = out_iw + ((size_t)(b0 + wv) * NT + t) * NS;
        ow[ln] = wxA; ow[ln + 64] = wxB;
      }
    }
    __syncthreads();
    // ---- gates MFMA: A=act (m=batch), B=wfrag (n=16 rows/wave) ----
    {
      const int br = (bn < 4) ? bn : 4;
      f32x4 acc = {0.f, 0.f, 0.f, 0.f};
      #pragma unroll
      for (int kk = 0; kk < 12; ++kk) {
        f16x8 a = *(const f16x8*)&sm.agxp[(size_t)br * SAG + kk * 32 + kq * 8];
        acc = __builtin_amdgcn_mfma_f32_16x16x32_f16(a, wfrag[kk], acc, 0, 0, 0);
      }
      if (ln < 16)
        *(f32x4*)&sm.gacc[(wv * 16 + ln) * 4] = acc;
    }
    __syncthreads();
    // ---- LSTM pointwise + publish h,c (own 64 units x 4 batches) ----
    if (tid < 256) {
      const int b = tid >> 6, ul = tid & 63;
      float gi = sm.gacc[(ul) * 4 + b]       + sm.gbias[ul];
      float gf = sm.gacc[(64 + ul) * 4 + b]  + sm.gbias[64 + ul];
      float gg = sm.gacc[(128 + ul) * 4 + b] + sm.gbias[128 + ul];
      float go = sm.gacc[(192 + ul) * 4 + b] + sm.gbias[192 + ul];
      float ii = 1.f / (1.f + __expf(-gi));
      float ff = 1.f / (1.f + __expf(-gf));
      float gt = 1.f - 2.f / (1.f + __expf(2.f * gg));
      float oo = 1.f / (1.f + __expf(-go));
      float c2 = ff * sm.cbuf[ul * 4 + b] + ii * gt;
      float h2 = oo * (1.f - 2.f / (1.f + __expf(2.f * c2)));
      sm.cbuf[ul * 4 + b] = c2;
      out_ie[((size_t)(b0 + b) * NT + t) * NH + u0 + ul] = h2;
      uint32_t* dst = ws + HC_OFF + ((size_t)(1 - par) * NGRP + g) * 1024 +
                      b * 256 + u0 + ul;
      awr(dst, __builtin_bit_cast(uint32_t, pk(h2, c2)));
    }
    __syncthreads();   // drains all waves' publishes before the counter bump
    if (tid == 0) cinc(cnt);
  }
}

extern "C" void kernel_launch(void* const* d_in, const int* in_sizes, int n_in,
                              void* d_out, int out_size, void* d_ws, size_t ws_size,
                              hipStream_t stream) {
  const float* x    = (const float*)d_in[0];
  const float* W_ah = (const float*)d_in[1];
  const float* b_ah = (const float*)d_in[2];
  const float* W_ai = (const float*)d_in[3];
  const float* b_ai = (const float*)d_in[4];
  const float* W_a  = (const float*)d_in[5];
  const float* b_a  = (const float*)d_in[6];
  const float* W_ih = (const float*)d_in[7];
  const float* W_hh = (const float*)d_in[8];
  const float* b_ih = (const float*)d_in[9];
  const float* b_hh = (const float*)d_in[10];
  float* out_iw = (float*)d_out;
  float* out_ie = (float*)d_out + (size_t)NB * NT * NS;
  uint32_t* ws = (uint32_t*)d_ws;

  hipLaunchKernelGGL(enc_init, dim3(256), dim3(256), 0, stream, ws);
  hipLaunchKernelGGL(enc_main, dim3(NWG), dim3(NTHR), 0, stream,
                     x, W_ah, b_ah, W_ai, b_ai, W_a, b_a, W_ih, W_hh, b_ih, b_hh,
                     out_iw, out_ie, ws);
}